// Round 1
// baseline (361.295 us; speedup 1.0000x reference)
//
#include <hip/hip_runtime.h>
#include <math.h>

// z:  (2,1,256,256,64)  idx = b*4194304 + x*16384 + y*64 + k
// tg: (2,3,256,256,64)  idx = b*12582912 + c*4194304 + x*16384 + y*64 + k
// ws (doubles): [0]=smooth_sum, [1]=div_sum, [2+b*64+k]=s1, [130+... wait 2+128+b*64+k]=s2
//   total 258 doubles

#define XSTRIDE 16384
#define YSTRIDE 64
#define ROWS_PER_WAVE 32

__device__ __forceinline__ float shd(float v) { return __shfl_down(v, 1, 64); }

__global__ __launch_bounds__(512) void zero_ws_kernel(double* ws) {
    int i = threadIdx.x;
    if (i < 258) ws[i] = 0.0;
}

__global__ __launch_bounds__(256) void fused_loss_kernel(
    const float* __restrict__ zin, const float* __restrict__ tg,
    double* __restrict__ ws)
{
    const int lane = threadIdx.x & 63;
    const int wave = blockIdx.x * 4 + (threadIdx.x >> 6);
    const int r0 = wave * ROWS_PER_WAVE;     // rows: r = b*65536 + x*256 + y
    const int b  = r0 >> 16;                 // constant per wave (32 | 65536)
    const int x  = (r0 & 65535) >> 8;        // constant per wave (32 | 256)
    const int y0 = r0 & 255;

    const float* zb  = zin + ((size_t)b << 22);
    const float* bxb = tg  + ((size_t)(b * 3) << 22);
    const float* byb = bxb + (1u << 22);
    const float* bzb = byb + (1u << 22);

    const bool xlo = (x >= 1), xhi = (x < 255);
    const bool lk  = (lane < 63);

    float sm_acc = 0.f, dv_acc = 0.f, s1 = 0.f, s2 = 0.f;

    int base = x * XSTRIDE + y0 * YSTRIDE + lane;
    #pragma unroll 1
    for (int it = 0; it < ROWS_PER_WAVE; ++it, base += YSTRIDE) {
        const int y = y0 + it;
        const bool do_div = xhi && (y < 255);
        const bool do_sm  = do_div && xlo && (y >= 1);

        float z00  = zb[base];
        float z00p = shd(z00);
        float dz00 = z00p - z00;
        if (lk) { s1 += dz00; s2 += dz00 * dz00; }
        float d2c = dz00 * dz00;

        if (do_div) {
            float z10 = zb[base + XSTRIDE];
            float z01 = zb[base + YSTRIDE];
            float z11 = zb[base + XSTRIDE + YSTRIDE];
            float z10p = shd(z10), z01p = shd(z01), z11p = shd(z11);
            float dz10 = z10p - z10, dz01 = z01p - z01, dz11 = z11p - z11;

            if (do_sm) {
                float zm0 = zb[base - XSTRIDE];
                float z0m = zb[base - YSTRIDE];
                float dm0 = shd(zm0) - zm0;  float d2xm = dm0 * dm0;
                float d0m = shd(z0m) - z0m;  float d2ym = d0m * d0m;
                float d2xp = dz10 * dz10;
                float d2yp = dz01 * dz01;
                float d2km = __shfl_up(d2c, 1, 64);
                float d2kp = shd(d2c);
                if (lane >= 1 && lane <= 61) {
                    float lap = 6.f * d2c - d2xm - d2xp - d2ym - d2yp - d2kp - d2km;
                    sm_acc += lap * lap;
                }
            }

            float bx00 = bxb[base],           bx10 = bxb[base + XSTRIDE];
            float bx01 = bxb[base + YSTRIDE], bx11 = bxb[base + XSTRIDE + YSTRIDE];
            float by00 = byb[base],           by10 = byb[base + XSTRIDE];
            float by01 = byb[base + YSTRIDE], by11 = byb[base + XSTRIDE + YSTRIDE];
            float bz00 = bzb[base],           bz10 = bzb[base + XSTRIDE];
            float bz01 = bzb[base + YSTRIDE], bz11 = bzb[base + XSTRIDE + YSTRIDE];

            float bx00p = shd(bx00), bx10p = shd(bx10), bx01p = shd(bx01), bx11p = shd(bx11);
            float by00p = shd(by00), by10p = shd(by10), by01p = shd(by01), by11p = shd(by11);
            float bzs4  = bz00 + bz01 + bz10 + bz11;
            float bzs4p = shd(bzs4);

            float adz00 = fabsf(dz00), adz10 = fabsf(dz10);
            float adz01 = fabsf(dz01), adz11 = fabsf(dz11);

            float num =
                  0.125f * (bx10 + bx11 + bx10p + bx11p) * (adz10 + adz11)
                - 0.125f * (bx00 + bx01 + bx00p + bx01p) * (adz00 + adz01)
                + 0.125f * (by01 + by11 + by01p + by11p) * (adz01 + adz11)
                - 0.125f * (by00 + by10 + by00p + by10p) * (adz00 + adz10)
                + 0.25f  * (bzs4p - bzs4);
            const float c6 = 1.0f / 6.0f;
            num += c6 * ( (bx00p + bx10p + bx11p) * (z00p - z10p)
                        + (bx01p + bx11p + bx10p) * (z01p - z11p)
                        + (by10p + by11p + by01p) * (z10p - z11p)
                        + (by00p + by01p + by11p) * (z00p - z01p)
                        - (bx00 + bx10 + bx11) * (z00 - z10)
                        - (bx01 + bx11 + bx10) * (z01 - z11)
                        - (by10 + by11 + by01) * (z10 - z11)
                        - (by00 + by01 + by11) * (z00 - z01) );

            float sbx = bx00 + bx01 + bx10 + bx11 + bx00p + bx01p + bx10p + bx11p;
            float sby = by00 + by01 + by10 + by11 + by00p + by01p + by10p + by11p;
            float sbz = bzs4 + bzs4p;
            float den = 0.015625f * (sbx * sbx + sby * sby + sbz * sbz) + 1e-10f;
            if (lk) dv_acc += num * num / den;
        }
    }

    // wave butterfly reduce the two scalar sums
    #pragma unroll
    for (int off = 32; off > 0; off >>= 1) {
        sm_acc += __shfl_down(sm_acc, off, 64);
        dv_acc += __shfl_down(dv_acc, off, 64);
    }
    if (lane == 0) {
        atomicAdd(&ws[0], (double)sm_acc);
        atomicAdd(&ws[1], (double)dv_acc);
    }
    if (lk) {
        atomicAdd(&ws[2 + b * 64 + lane],       (double)s1);
        atomicAdd(&ws[2 + 128 + b * 64 + lane], (double)s2);
    }
}

__global__ __launch_bounds__(128) void finalize_kernel(const double* __restrict__ ws,
                                                       float* __restrict__ out)
{
    __shared__ double red[128];
    const int t = threadIdx.x;
    double stdv = 0.0;
    {
        int k = t & 63, b = t >> 6;
        if (k < 63) {
            double s1 = ws[2 + b * 64 + k];
            double s2 = ws[2 + 128 + b * 64 + k];
            const double N = 65536.0;
            double var = (s2 - s1 * s1 / N) / (N - 1.0);
            stdv = sqrt(var > 0.0 ? var : 0.0);
        }
    }
    red[t] = stdv;
    __syncthreads();
    for (int off = 64; off > 0; off >>= 1) {
        if (t < off) red[t] += red[t + off];
        __syncthreads();
    }
    if (t == 0) {
        double loss_std    = red[0] / 126.0;
        double loss_smooth = ws[0] / (2.0 * 254.0 * 254.0 * 61.0);
        double loss_div    = ws[1] / (2.0 * 255.0 * 255.0 * 63.0);
        out[0] = (float)(loss_div * 1e9);
        out[1] = (float)(loss_smooth * 10.0 + loss_std * 100.0);
    }
}

extern "C" void kernel_launch(void* const* d_in, const int* in_sizes, int n_in,
                              void* d_out, int out_size, void* d_ws, size_t ws_size,
                              hipStream_t stream) {
    const float* z  = (const float*)d_in[0];   // outputs (2,1,256,256,64)
    const float* tg = (const float*)d_in[1];   // targets (2,3,256,256,64)
    float* out = (float*)d_out;
    double* ws = (double*)d_ws;

    zero_ws_kernel<<<1, 512, 0, stream>>>(ws);
    // 131072 rows total / 32 rows per wave = 4096 waves = 1024 blocks of 4 waves
    fused_loss_kernel<<<1024, 256, 0, stream>>>(z, tg, ws);
    finalize_kernel<<<1, 128, 0, stream>>>(ws, out);
}

// Round 2
// 289.423 us; speedup vs baseline: 1.2483x; 1.2483x over previous
//
#include <hip/hip_runtime.h>
#include <math.h>

// z:  (2,1,256,256,64)  idx = b*4194304 + x*16384 + y*64 + k
// tg: (2,3,256,256,64)  idx = b*12582912 + c*4194304 + x*16384 + y*64 + k
// ws (floats): [0]=smooth_sum, [1]=div_sum, [2+b*64+k]=s1, [130+b*64+k]=s2  (258 total)

#define XS 16384
#define YS 64
#define RPW 16   // rows per wave; wave's rows share b and x (16 | 256)

__device__ __forceinline__ float shd(float v) { return __shfl_down(v, 1, 64); }

__global__ __launch_bounds__(512) void zero_ws_kernel(float* ws) {
    int i = threadIdx.x;
    if (i < 258) ws[i] = 0.0f;
}

__global__ __launch_bounds__(256, 8) void fused_loss_kernel(
    const float* __restrict__ zin, const float* __restrict__ tg,
    float* __restrict__ ws)
{
    const int lane = threadIdx.x & 63;
    const int w    = threadIdx.x >> 6;
    const int wave = blockIdx.x * 4 + w;
    const int r0 = wave * RPW;              // row = b*65536 + x*256 + y
    const int b  = r0 >> 16;
    const int x  = (r0 & 65535) >> 8;
    const int y0 = r0 & 255;

    const float* zb  = zin + ((size_t)b << 22);
    const float* bxb = tg  + ((size_t)(b * 3) << 22);
    const float* byb = bxb + (1u << 22);
    const float* bzb = byb + (1u << 22);

    const bool xlo = (x >= 1), xhi = (x < 255);
    const bool lk  = (lane < 63);

    float sm_acc = 0.f, dv_acc = 0.f, s1 = 0.f, s2 = 0.f;

    int base = x * XS + y0 * YS + lane;

    // ---- prologue: load row y0 state ----
    float cz0, cz1 = 0.f, cdz0, cdz1 = 0.f, cdm = 0.f;
    float cbx0 = 0.f, cbx1 = 0.f, cbx0p = 0.f, cbx1p = 0.f;
    float cby0 = 0.f, cby1 = 0.f, cby0p = 0.f, cby1p = 0.f;
    float cbzs = 0.f, cbzsp = 0.f;
    float d2prev = 0.f;

    cz0  = zb[base];
    cdz0 = shd(cz0) - cz0;
    if (xhi) {
        cz1  = zb[base + XS];
        cdz1 = shd(cz1) - cz1;
        cbx0 = bxb[base];      cbx1 = bxb[base + XS];
        cby0 = byb[base];      cby1 = byb[base + XS];
        float bz0 = bzb[base], bz1 = bzb[base + XS];
        cbzs  = bz0 + bz1;
        cbx0p = shd(cbx0); cbx1p = shd(cbx1);
        cby0p = shd(cby0); cby1p = shd(cby1);
        cbzsp = shd(cbzs);
    }
    if (xlo) {
        float czm = zb[base - XS];
        cdm = shd(czm) - czm;
    }
    if (y0 >= 1) {
        float zpm = zb[base - YS];
        float t = shd(zpm) - zpm;
        d2prev = t * t;
    }

    #pragma unroll 1
    for (int it = 0; it < RPW; ++it, base += YS) {
        const int y = y0 + it;
        const bool hn = (y < 255);

        // ---- loads for row y+1 ----
        float nz0 = 0.f, nz1 = 0.f, nzm = 0.f;
        float nbx0 = 0.f, nbx1 = 0.f, nby0 = 0.f, nby1 = 0.f, nbz0 = 0.f, nbz1 = 0.f;
        if (hn) {
            nz0 = zb[base + YS];
            if (xhi) {
                nz1  = zb[base + XS + YS];
                nbx0 = bxb[base + YS];      nbx1 = bxb[base + XS + YS];
                nby0 = byb[base + YS];      nby1 = byb[base + XS + YS];
                nbz0 = bzb[base + YS];      nbz1 = bzb[base + XS + YS];
            }
            if (xlo) nzm = zb[base - XS + YS];
        }
        float ndz0 = shd(nz0) - nz0;
        float ndz1 = shd(nz1) - nz1;
        float ndm  = shd(nzm) - nzm;
        float nbx0p = shd(nbx0), nbx1p = shd(nbx1);
        float nby0p = shd(nby0), nby1p = shd(nby1);
        float nbzs  = nbz0 + nbz1;
        float nbzsp = shd(nbzs);

        // ---- compute row y ----
        float dz00 = cdz0;
        if (lk) { s1 += dz00; s2 += dz00 * dz00; }
        float d2c = dz00 * dz00;

        if (xhi && hn) {
            float dz10 = cdz1, dz01 = ndz0, dz11 = ndz1;

            if (xlo && y >= 1) {
                float d2xm = cdm * cdm;
                float d2ym = d2prev;
                float d2xp = dz10 * dz10;
                float d2yp = dz01 * dz01;
                float d2km = __shfl_up(d2c, 1, 64);
                float d2kp = shd(d2c);
                if (lane >= 1 && lane <= 61) {
                    float lap = 6.f * d2c - d2xm - d2xp - d2ym - d2yp - d2kp - d2km;
                    sm_acc += lap * lap;
                }
            }

            float adz00 = fabsf(dz00), adz10 = fabsf(dz10);
            float adz01 = fabsf(dz01), adz11 = fabsf(dz11);

            float z00p = cz0 + dz00, z10p = cz1 + dz10;
            float z01p = nz0 + dz01, z11p = nz1 + dz11;

            float bzs4  = cbzs + nbzs;
            float bzs4p = cbzsp + nbzsp;

            float num =
                  0.125f * (cbx1 + nbx1 + cbx1p + nbx1p) * (adz10 + adz11)
                - 0.125f * (cbx0 + nbx0 + cbx0p + nbx0p) * (adz00 + adz01)
                + 0.125f * (nby0 + nby1 + nby0p + nby1p) * (adz01 + adz11)
                - 0.125f * (cby0 + cby1 + cby0p + cby1p) * (adz00 + adz10)
                + 0.25f  * (bzs4p - bzs4);
            const float c6 = 1.0f / 6.0f;
            num += c6 * ( (cbx0p + cbx1p + nbx1p) * (z00p - z10p)
                        + (nbx0p + nbx1p + cbx1p) * (z01p - z11p)
                        + (cby1p + nby1p + nby0p) * (z10p - z11p)
                        + (cby0p + nby0p + nby1p) * (z00p - z01p)
                        - (cbx0 + cbx1 + nbx1) * (cz0 - cz1)
                        - (nbx0 + nbx1 + cbx1) * (nz0 - nz1)
                        - (cby1 + nby1 + nby0) * (cz1 - nz1)
                        - (cby0 + nby0 + nby1) * (cz0 - nz0) );

            float sbx = cbx0 + cbx1 + nbx0 + nbx1 + cbx0p + cbx1p + nbx0p + nbx1p;
            float sby = cby0 + cby1 + nby0 + nby1 + cby0p + cby1p + nby0p + nby1p;
            float sbz = bzs4 + bzs4p;
            float den = 0.015625f * (sbx * sbx + sby * sby + sbz * sbz) + 1e-10f;
            if (lk) dv_acc += num * num / den;
        }

        // ---- roll ----
        d2prev = d2c;
        cz0 = nz0; cz1 = nz1; cdz0 = ndz0; cdz1 = ndz1; cdm = ndm;
        cbx0 = nbx0; cbx1 = nbx1; cbx0p = nbx0p; cbx1p = nbx1p;
        cby0 = nby0; cby1 = nby1; cby0p = nby0p; cby1p = nby1p;
        cbzs = nbzs; cbzsp = nbzsp;
    }

    // ---- reduction: wave butterfly for scalars, LDS across 4 waves ----
    #pragma unroll
    for (int off = 32; off > 0; off >>= 1) {
        sm_acc += __shfl_down(sm_acc, off, 64);
        dv_acc += __shfl_down(dv_acc, off, 64);
    }

    __shared__ float rS1[4][64];
    __shared__ float rS2[4][64];
    __shared__ float rSC[4][2];
    rS1[w][lane] = s1;
    rS2[w][lane] = s2;
    if (lane == 0) { rSC[w][0] = sm_acc; rSC[w][1] = dv_acc; }
    __syncthreads();
    if (w == 0) {
        float t1 = rS1[0][lane] + rS1[1][lane] + rS1[2][lane] + rS1[3][lane];
        float t2 = rS2[0][lane] + rS2[1][lane] + rS2[2][lane] + rS2[3][lane];
        if (lane < 63) {
            atomicAdd(&ws[2 + b * 64 + lane],   t1);
            atomicAdd(&ws[130 + b * 64 + lane], t2);
        }
        if (lane == 0) atomicAdd(&ws[0], rSC[0][0] + rSC[1][0] + rSC[2][0] + rSC[3][0]);
        if (lane == 1) atomicAdd(&ws[1], rSC[0][1] + rSC[1][1] + rSC[2][1] + rSC[3][1]);
    }
}

__global__ __launch_bounds__(128) void finalize_kernel(const float* __restrict__ ws,
                                                       float* __restrict__ out)
{
    __shared__ double red[128];
    const int t = threadIdx.x;
    double stdv = 0.0;
    {
        int k = t & 63, b = t >> 6;
        if (k < 63) {
            double s1 = (double)ws[2 + b * 64 + k];
            double s2 = (double)ws[130 + b * 64 + k];
            const double N = 65536.0;
            double var = (s2 - s1 * s1 / N) / (N - 1.0);
            stdv = sqrt(var > 0.0 ? var : 0.0);
        }
    }
    red[t] = stdv;
    __syncthreads();
    for (int off = 64; off > 0; off >>= 1) {
        if (t < off) red[t] += red[t + off];
        __syncthreads();
    }
    if (t == 0) {
        double loss_std    = red[0] / 126.0;
        double loss_smooth = (double)ws[0] / (2.0 * 254.0 * 254.0 * 61.0);
        double loss_div    = (double)ws[1] / (2.0 * 255.0 * 255.0 * 63.0);
        out[0] = (float)(loss_div * 1e9);
        out[1] = (float)(loss_smooth * 10.0 + loss_std * 100.0);
    }
}

extern "C" void kernel_launch(void* const* d_in, const int* in_sizes, int n_in,
                              void* d_out, int out_size, void* d_ws, size_t ws_size,
                              hipStream_t stream) {
    const float* z  = (const float*)d_in[0];   // outputs (2,1,256,256,64)
    const float* tg = (const float*)d_in[1];   // targets (2,3,256,256,64)
    float* out = (float*)d_out;
    float* ws = (float*)d_ws;

    zero_ws_kernel<<<1, 512, 0, stream>>>(ws);
    // 131072 rows / 16 rows per wave = 8192 waves = 2048 blocks x 4 waves (32 waves/CU)
    fused_loss_kernel<<<2048, 256, 0, stream>>>(z, tg, ws);
    finalize_kernel<<<1, 128, 0, stream>>>(ws, out);
}

// Round 3
// 278.934 us; speedup vs baseline: 1.2953x; 1.0376x over previous
//
#include <hip/hip_runtime.h>
#include <math.h>

// z:  (2,1,256,256,64)  idx = b*4194304 + x*16384 + y*64 + k
// tg: (2,3,256,256,64)  idx = b*12582912 + c*4194304 + x*16384 + y*64 + k
// ws (floats): [0]=smooth_sum, [1]=div_sum, [2+b*64+k]=s1, [130+b*64+k]=s2  (258 total)

#define XS 16384
#define YS 64
#define RPW 16   // rows per wave; wave's rows share b and x (16 | 256)

__device__ __forceinline__ float shd(float v) { return __shfl_down(v, 1, 64); }

__global__ __launch_bounds__(512) void zero_ws_kernel(float* ws) {
    int i = threadIdx.x;
    if (i < 258) ws[i] = 0.0f;
}

// NOTE: plain launch_bounds(256) — round 2 showed (256,8) forces VGPR=32 with
// ~65 MB of scratch spill traffic. Round-1-style body compiles to 44 VGPR,
// which already permits 8 waves/SIMD.
__global__ __launch_bounds__(256) void fused_loss_kernel(
    const float* __restrict__ zin, const float* __restrict__ tg,
    float* __restrict__ ws)
{
    const int lane = threadIdx.x & 63;
    const int w    = threadIdx.x >> 6;
    const int wave = blockIdx.x * 4 + w;
    const int r0 = wave * RPW;              // row = b*65536 + x*256 + y
    const int b  = r0 >> 16;
    const int x  = (r0 & 65535) >> 8;
    const int y0 = r0 & 255;

    const float* zb  = zin + ((size_t)b << 22);
    const float* bxb = tg  + ((size_t)(b * 3) << 22);
    const float* byb = bxb + (1u << 22);
    const float* bzb = byb + (1u << 22);

    const bool xlo = (x >= 1), xhi = (x < 255);
    const bool lk  = (lane < 63);

    float sm_acc = 0.f, dv_acc = 0.f, s1 = 0.f, s2 = 0.f;

    int base = x * XS + y0 * YS + lane;
    #pragma unroll 1
    for (int it = 0; it < RPW; ++it, base += YS) {
        const int y = y0 + it;
        const bool do_div = xhi && (y < 255);
        const bool do_sm  = do_div && xlo && (y >= 1);

        float z00  = zb[base];
        float z00p = shd(z00);
        float dz00 = z00p - z00;
        if (lk) { s1 += dz00; s2 += dz00 * dz00; }
        float d2c = dz00 * dz00;

        if (do_div) {
            float z10 = zb[base + XS];
            float z01 = zb[base + YS];
            float z11 = zb[base + XS + YS];
            float z10p = shd(z10), z01p = shd(z01), z11p = shd(z11);
            float dz10 = z10p - z10, dz01 = z01p - z01, dz11 = z11p - z11;

            if (do_sm) {
                float zm0 = zb[base - XS];
                float z0m = zb[base - YS];
                float dm0 = shd(zm0) - zm0;  float d2xm = dm0 * dm0;
                float d0m = shd(z0m) - z0m;  float d2ym = d0m * d0m;
                float d2xp = dz10 * dz10;
                float d2yp = dz01 * dz01;
                float d2km = __shfl_up(d2c, 1, 64);
                float d2kp = shd(d2c);
                if (lane >= 1 && lane <= 61) {
                    float lap = 6.f * d2c - d2xm - d2xp - d2ym - d2yp - d2kp - d2km;
                    sm_acc += lap * lap;
                }
            }

            float bx00 = bxb[base],           bx10 = bxb[base + XS];
            float bx01 = bxb[base + YS], bx11 = bxb[base + XS + YS];
            float by00 = byb[base],           by10 = byb[base + XS];
            float by01 = byb[base + YS], by11 = byb[base + XS + YS];
            float bz00 = bzb[base],           bz10 = bzb[base + XS];
            float bz01 = bzb[base + YS], bz11 = bzb[base + XS + YS];

            float bx00p = shd(bx00), bx10p = shd(bx10), bx01p = shd(bx01), bx11p = shd(bx11);
            float by00p = shd(by00), by10p = shd(by10), by01p = shd(by01), by11p = shd(by11);
            float bzs4  = bz00 + bz01 + bz10 + bz11;
            float bzs4p = shd(bzs4);

            float adz00 = fabsf(dz00), adz10 = fabsf(dz10);
            float adz01 = fabsf(dz01), adz11 = fabsf(dz11);

            float num =
                  0.125f * (bx10 + bx11 + bx10p + bx11p) * (adz10 + adz11)
                - 0.125f * (bx00 + bx01 + bx00p + bx01p) * (adz00 + adz01)
                + 0.125f * (by01 + by11 + by01p + by11p) * (adz01 + adz11)
                - 0.125f * (by00 + by10 + by00p + by10p) * (adz00 + adz10)
                + 0.25f  * (bzs4p - bzs4);
            const float c6 = 1.0f / 6.0f;
            num += c6 * ( (bx00p + bx10p + bx11p) * (z00p - z10p)
                        + (bx01p + bx11p + bx10p) * (z01p - z11p)
                        + (by10p + by11p + by01p) * (z10p - z11p)
                        + (by00p + by01p + by11p) * (z00p - z01p)
                        - (bx00 + bx10 + bx11) * (z00 - z10)
                        - (bx01 + bx11 + bx10) * (z01 - z11)
                        - (by10 + by11 + by01) * (z10 - z11)
                        - (by00 + by01 + by11) * (z00 - z01) );

            float sbx = bx00 + bx01 + bx10 + bx11 + bx00p + bx01p + bx10p + bx11p;
            float sby = by00 + by01 + by10 + by11 + by00p + by01p + by10p + by11p;
            float sbz = bzs4 + bzs4p;
            float den = 0.015625f * (sbx * sbx + sby * sby + sbz * sbz) + 1e-10f;
            if (lk) dv_acc += num * num / den;
        }
    }

    // ---- reduction: wave butterfly for scalars, LDS across 4 waves ----
    #pragma unroll
    for (int off = 32; off > 0; off >>= 1) {
        sm_acc += __shfl_down(sm_acc, off, 64);
        dv_acc += __shfl_down(dv_acc, off, 64);
    }

    __shared__ float rS1[4][64];
    __shared__ float rS2[4][64];
    __shared__ float rSC[4][2];
    rS1[w][lane] = s1;
    rS2[w][lane] = s2;
    if (lane == 0) { rSC[w][0] = sm_acc; rSC[w][1] = dv_acc; }
    __syncthreads();
    if (w == 0) {
        float t1 = rS1[0][lane] + rS1[1][lane] + rS1[2][lane] + rS1[3][lane];
        float t2 = rS2[0][lane] + rS2[1][lane] + rS2[2][lane] + rS2[3][lane];
        if (lane < 63) {
            atomicAdd(&ws[2 + b * 64 + lane],   t1);
            atomicAdd(&ws[130 + b * 64 + lane], t2);
        }
        if (lane == 0) atomicAdd(&ws[0], rSC[0][0] + rSC[1][0] + rSC[2][0] + rSC[3][0]);
        if (lane == 1) atomicAdd(&ws[1], rSC[0][1] + rSC[1][1] + rSC[2][1] + rSC[3][1]);
    }
}

__global__ __launch_bounds__(128) void finalize_kernel(const float* __restrict__ ws,
                                                       float* __restrict__ out)
{
    __shared__ double red[128];
    const int t = threadIdx.x;
    double stdv = 0.0;
    {
        int k = t & 63, b = t >> 6;
        if (k < 63) {
            double s1 = (double)ws[2 + b * 64 + k];
            double s2 = (double)ws[130 + b * 64 + k];
            const double N = 65536.0;
            double var = (s2 - s1 * s1 / N) / (N - 1.0);
            stdv = sqrt(var > 0.0 ? var : 0.0);
        }
    }
    red[t] = stdv;
    __syncthreads();
    for (int off = 64; off > 0; off >>= 1) {
        if (t < off) red[t] += red[t + off];
        __syncthreads();
    }
    if (t == 0) {
        double loss_std    = red[0] / 126.0;
        double loss_smooth = (double)ws[0] / (2.0 * 254.0 * 254.0 * 61.0);
        double loss_div    = (double)ws[1] / (2.0 * 255.0 * 255.0 * 63.0);
        out[0] = (float)(loss_div * 1e9);
        out[1] = (float)(loss_smooth * 10.0 + loss_std * 100.0);
    }
}

extern "C" void kernel_launch(void* const* d_in, const int* in_sizes, int n_in,
                              void* d_out, int out_size, void* d_ws, size_t ws_size,
                              hipStream_t stream) {
    const float* z  = (const float*)d_in[0];   // outputs (2,1,256,256,64)
    const float* tg = (const float*)d_in[1];   // targets (2,3,256,256,64)
    float* out = (float*)d_out;
    float* ws = (float*)d_ws;

    zero_ws_kernel<<<1, 512, 0, stream>>>(ws);
    // 131072 rows / 16 rows per wave = 8192 waves = 2048 blocks x 4 waves (32 waves/CU)
    fused_loss_kernel<<<2048, 256, 0, stream>>>(z, tg, ws);
    finalize_kernel<<<1, 128, 0, stream>>>(ws, out);
}

// Round 4
// 206.794 us; speedup vs baseline: 1.7471x; 1.3489x over previous
//
#include <hip/hip_runtime.h>
#include <math.h>

// z:  (2,1,256,256,64)  idx = b*4194304 + x*16384 + y*64 + k
// tg: (2,3,256,256,64)  idx = b*12582912 + c*4194304 + x*16384 + y*64 + k
//
// Tiled stencil: block = 4x4 cells (x0..x0+3, y0..y0+3), full k (64).
// LDS: z strips x0-1..x0+4 (6) x rows y0-1..y0+4 (6); b fields x0..x0+4 (5) x y0..y0+4 (5).
// Strips padded +4 floats to de-phase bank patterns while keeping 16B alignment.
//
// ws layout (floats), 32 slices x 258:
//   sl[p*258 + 0]=smooth, +1=div, +2+b*64+k = s1, +130+b*64+k = s2

#define ZSTR 388            // 6*64 + 4 pad
#define BSTR 324            // 5*64 + 4 pad
#define BFLD 1620           // 5*BSTR

__global__ __launch_bounds__(512) void zero_ws_kernel(float* ws) {
    for (int i = threadIdx.x; i < 32 * 258; i += 512) ws[i] = 0.0f;
}

#define LD5(arr, p) do { \
    float4 _a = *(const float4*)(p); float4 _b = *(const float4*)((p) + 4); \
    arr[0] = _a.x; arr[1] = _a.y; arr[2] = _a.z; arr[3] = _a.w; arr[4] = _b.x; } while (0)

__global__ __launch_bounds__(256, 4) void fused_loss_kernel(
    const float* __restrict__ zin, const float* __restrict__ tg,
    float* __restrict__ ws)
{
    __shared__ float zs[6 * ZSTR];       // 2328 floats
    __shared__ float bs[3 * BFLD];       // 4860 floats
    __shared__ float rsc[4][2];

    const int tid  = threadIdx.x;
    const int lane = tid & 63;
    const int w    = tid >> 6;

    const int bb = blockIdx.x >> 12;
    const int rest = blockIdx.x & 4095;
    const int x0 = ((rest >> 6) & 63) << 2;
    const int y0 = (rest & 63) << 2;

    const float* zg = zin + ((size_t)bb << 22);

    // ---- cooperative staging: 576 z float4s + 1200 b float4s ----
    for (int i = tid; i < 1776; i += 256) {
        if (i < 576) {
            int row = i >> 4;
            int o   = (i & 15) << 2;
            int xi  = row / 6;
            int yr  = row - xi * 6;
            int x = x0 - 1 + xi; x = x < 0 ? 0 : (x > 255 ? 255 : x);
            int y = y0 - 1 + yr; y = y < 0 ? 0 : (y > 255 ? 255 : y);
            *(float4*)&zs[xi * ZSTR + yr * 64 + o] =
                *(const float4*)&zg[x * 16384 + y * 64 + o];
        } else {
            int j  = i - 576;
            int f  = j / 400;
            int jj = j - f * 400;
            int row = jj >> 4;
            int o   = (jj & 15) << 2;
            int xi  = row / 5;
            int yr  = row - xi * 5;
            int x = x0 + xi; x = x > 255 ? 255 : x;
            int y = y0 + yr; y = y > 255 ? 255 : y;
            const float* g = tg + ((size_t)(bb * 3 + f) << 22);
            *(float4*)&bs[f * BFLD + xi * BSTR + yr * 64 + o] =
                *(const float4*)&g[x * 16384 + y * 64 + o];
        }
    }
    __syncthreads();

    // ---- compute: thread = (cell, k-quad) ----
    const int c  = tid >> 4;
    const int kq = tid & 15;
    const int cx = c & 3, cy = c >> 2;
    const int xg = x0 + cx, yg = y0 + cy;
    const int k0 = kq << 2;

    const float* zC = &zs[(cx + 1) * ZSTR + (cy + 1) * 64 + k0];

    float zcv[7];
    {
        float4 m = *(const float4*)(zC - 4);
        float4 a = *(const float4*)(zC);
        float4 b = *(const float4*)(zC + 4);
        zcv[0] = m.w; zcv[1] = a.x; zcv[2] = a.y; zcv[3] = a.z; zcv[4] = a.w;
        zcv[5] = b.x; zcv[6] = b.y;
    }
    float zEv[5];  LD5(zEv,  zC + ZSTR);
    float zWv[5];  LD5(zWv,  zC - ZSTR);
    float zNv[5];  LD5(zNv,  zC + 64);
    float zSv[5];  LD5(zSv,  zC - 64);
    float zNEv[5]; LD5(zNEv, zC + ZSTR + 64);

    float dz0[4], dzE[4], dzN[4], dzNE[4];
    #pragma unroll
    for (int e = 0; e < 4; ++e) {
        dz0[e]  = zcv[e + 2] - zcv[e + 1];
        dzE[e]  = zEv[e + 1] - zEv[e];
        dzN[e]  = zNv[e + 1] - zNv[e];
        dzNE[e] = zNEv[e + 1] - zNEv[e];
    }

    // std partials (per-k): k<63 valid
    float s1a[4], s2a[4];
    #pragma unroll
    for (int e = 0; e < 4; ++e) {
        bool kok = (k0 + e) < 63;
        s1a[e] = kok ? dz0[e] : 0.0f;
        s2a[e] = kok ? dz0[e] * dz0[e] : 0.0f;
    }

    // smooth
    float sm = 0.0f;
    if (xg >= 1 && xg <= 254 && yg >= 1 && yg <= 254) {
        #pragma unroll
        for (int e = 0; e < 4; ++e) {
            int k = k0 + e;
            if (k >= 1 && k <= 61) {
                float dzm = zcv[e + 1] - zcv[e];
                float dzp = zcv[e + 3] - zcv[e + 2];
                float dzw = zWv[e + 1] - zWv[e];
                float dzs = zSv[e + 1] - zSv[e];
                float lap = 6.0f * dz0[e] * dz0[e]
                          - dzw * dzw - dzE[e] * dzE[e]
                          - dzs * dzs - dzN[e] * dzN[e]
                          - dzm * dzm - dzp * dzp;
                sm += lap * lap;
            }
        }
    }

    // div
    float dv = 0.0f;
    if (xg < 255 && yg < 255) {
        const float* bxP = &bs[cx * BSTR + cy * 64 + k0];
        const float* byP = bxP + BFLD;
        const float* bzP = byP + BFLD;
        float bx00v[5]; LD5(bx00v, bxP);
        float bx10v[5]; LD5(bx10v, bxP + BSTR);
        float bx01v[5]; LD5(bx01v, bxP + 64);
        float bx11v[5]; LD5(bx11v, bxP + BSTR + 64);
        float by00v[5]; LD5(by00v, byP);
        float by10v[5]; LD5(by10v, byP + BSTR);
        float by01v[5]; LD5(by01v, byP + 64);
        float by11v[5]; LD5(by11v, byP + BSTR + 64);
        float bz00v[5]; LD5(bz00v, bzP);
        float bz10v[5]; LD5(bz10v, bzP + BSTR);
        float bz01v[5]; LD5(bz01v, bzP + 64);
        float bz11v[5]; LD5(bz11v, bzP + BSTR + 64);

        const float c6 = 1.0f / 6.0f;
        #pragma unroll
        for (int e = 0; e < 4; ++e) {
            if ((k0 + e) < 63) {
                float adz00 = fabsf(dz0[e]),  adz10 = fabsf(dzE[e]);
                float adz01 = fabsf(dzN[e]),  adz11 = fabsf(dzNE[e]);

                float num =
                    0.125f * ( (bx10v[e] + bx10v[e+1] + bx11v[e] + bx11v[e+1]) * (adz10 + adz11)
                             - (bx00v[e] + bx00v[e+1] + bx01v[e] + bx01v[e+1]) * (adz00 + adz01)
                             + (by01v[e] + by01v[e+1] + by11v[e] + by11v[e+1]) * (adz01 + adz11)
                             - (by00v[e] + by00v[e+1] + by10v[e] + by10v[e+1]) * (adz00 + adz10) )
                  + 0.25f * ( (bz00v[e+1] + bz10v[e+1] + bz01v[e+1] + bz11v[e+1])
                            - (bz00v[e]   + bz10v[e]   + bz01v[e]   + bz11v[e]) );

                num += c6 * ( (bx00v[e+1] + bx10v[e+1] + bx11v[e+1]) * (zcv[e+2] - zEv[e+1])
                            + (bx01v[e+1] + bx11v[e+1] + bx10v[e+1]) * (zNv[e+1] - zNEv[e+1])
                            + (by10v[e+1] + by11v[e+1] + by01v[e+1]) * (zEv[e+1] - zNEv[e+1])
                            + (by00v[e+1] + by01v[e+1] + by11v[e+1]) * (zcv[e+2] - zNv[e+1])
                            - (bx00v[e] + bx10v[e] + bx11v[e]) * (zcv[e+1] - zEv[e])
                            - (bx01v[e] + bx11v[e] + bx10v[e]) * (zNv[e] - zNEv[e])
                            - (by10v[e] + by11v[e] + by01v[e]) * (zEv[e] - zNEv[e])
                            - (by00v[e] + by01v[e] + by11v[e]) * (zcv[e+1] - zNv[e]) );

                float sbx = bx00v[e] + bx00v[e+1] + bx10v[e] + bx10v[e+1]
                          + bx01v[e] + bx01v[e+1] + bx11v[e] + bx11v[e+1];
                float sby = by00v[e] + by00v[e+1] + by10v[e] + by10v[e+1]
                          + by01v[e] + by01v[e+1] + by11v[e] + by11v[e+1];
                float sbz = bz00v[e] + bz00v[e+1] + bz10v[e] + bz10v[e+1]
                          + bz01v[e] + bz01v[e+1] + bz11v[e] + bz11v[e+1];
                float den = 0.015625f * (sbx * sbx + sby * sby + sbz * sbz) + 1e-10f;
                dv += num * num / den;
            }
        }
    }

    // ---- block reduction ----
    #pragma unroll
    for (int off = 32; off > 0; off >>= 1) {
        sm += __shfl_down(sm, off, 64);
        dv += __shfl_down(dv, off, 64);
    }

    __syncthreads();   // all LDS reads done; safe to reuse zs
    float* r1 = zs;            // 1024 floats
    float* r2 = zs + 1024;     // 1024 floats
    { float4 v; v.x = s1a[0]; v.y = s1a[1]; v.z = s1a[2]; v.w = s1a[3];
      *(float4*)&r1[tid << 2] = v; }
    { float4 v; v.x = s2a[0]; v.y = s2a[1]; v.z = s2a[2]; v.w = s2a[3];
      *(float4*)&r2[tid << 2] = v; }
    if (lane == 0) { rsc[w][0] = sm; rsc[w][1] = dv; }
    __syncthreads();

    if (tid < 64) {
        float a = 0.0f, b2 = 0.0f;
        #pragma unroll
        for (int cc = 0; cc < 16; ++cc) {
            a  += r1[cc * 64 + tid];
            b2 += r2[cc * 64 + tid];
        }
        float* sl = ws + (blockIdx.x & 31) * 258;
        if (tid < 63) {
            atomicAdd(&sl[2 + bb * 64 + tid],   a);
            atomicAdd(&sl[130 + bb * 64 + tid], b2);
        }
        if (tid == 0) atomicAdd(&sl[0], rsc[0][0] + rsc[1][0] + rsc[2][0] + rsc[3][0]);
        if (tid == 1) atomicAdd(&sl[1], rsc[0][1] + rsc[1][1] + rsc[2][1] + rsc[3][1]);
    }
}

__global__ __launch_bounds__(128) void finalize_kernel(const float* __restrict__ ws,
                                                       float* __restrict__ out)
{
    __shared__ double red[128];
    const int t = threadIdx.x;
    double stdv = 0.0;
    {
        int k = t & 63, bb = t >> 6;
        if (k < 63) {
            double s1 = 0.0, s2 = 0.0;
            for (int p = 0; p < 32; ++p) {
                s1 += (double)ws[p * 258 + 2 + bb * 64 + k];
                s2 += (double)ws[p * 258 + 130 + bb * 64 + k];
            }
            const double N = 65536.0;
            double var = (s2 - s1 * s1 / N) / (N - 1.0);
            stdv = sqrt(var > 0.0 ? var : 0.0);
        }
    }
    red[t] = stdv;
    __syncthreads();
    for (int off = 64; off > 0; off >>= 1) {
        if (t < off) red[t] += red[t + off];
        __syncthreads();
    }
    if (t == 0) {
        double smt = 0.0, dvt = 0.0;
        for (int p = 0; p < 32; ++p) {
            smt += (double)ws[p * 258 + 0];
            dvt += (double)ws[p * 258 + 1];
        }
        double loss_std    = red[0] / 126.0;
        double loss_smooth = smt / (2.0 * 254.0 * 254.0 * 61.0);
        double loss_div    = dvt / (2.0 * 255.0 * 255.0 * 63.0);
        out[0] = (float)(loss_div * 1e9);
        out[1] = (float)(loss_smooth * 10.0 + loss_std * 100.0);
    }
}

extern "C" void kernel_launch(void* const* d_in, const int* in_sizes, int n_in,
                              void* d_out, int out_size, void* d_ws, size_t ws_size,
                              hipStream_t stream) {
    const float* z  = (const float*)d_in[0];   // outputs (2,1,256,256,64)
    const float* tg = (const float*)d_in[1];   // targets (2,3,256,256,64)
    float* out = (float*)d_out;
    float* ws  = (float*)d_ws;

    zero_ws_kernel<<<1, 512, 0, stream>>>(ws);
    // 64x64 tiles x 2 batches = 8192 blocks
    fused_loss_kernel<<<8192, 256, 0, stream>>>(z, tg, ws);
    finalize_kernel<<<1, 128, 0, stream>>>(ws, out);
}